// Round 5
// baseline (410.572 us; speedup 1.0000x reference)
//
#include <hip/hip_runtime.h>
#include <hip/hip_bf16.h>

#define N_NODES 50000
#define DIM 64
#define N_EDGES 800000
#define NTILES (N_EDGES / 16)

typedef short short8 __attribute__((ext_vector_type(8)));
typedef float f32x4 __attribute__((ext_vector_type(4)));

__device__ __forceinline__ float silu_f(float x) {
    return x * __builtin_amdgcn_rcpf(1.0f + __expf(-x));
}
// f32 -> bf16 round-to-nearest-even
__device__ __forceinline__ short f2bf(float f) {
    unsigned u = __builtin_bit_cast(unsigned, f);
    u += 0x7FFFu + ((u >> 16) & 1u);
    return (short)(u >> 16);
}

// ---------------- Kernel 0: hp = h + h_init; zero accumulators; detect eidx dtype ----------------
__global__ void k_init(const float* __restrict__ h, const float* __restrict__ h_init,
                       float* __restrict__ hp, float* __restrict__ agg,
                       float* __restrict__ posw, float* __restrict__ deg,
                       const void* __restrict__ eidx, int* __restrict__ flag) {
    int i = blockIdx.x * blockDim.x + threadIdx.x;
    int stride = gridDim.x * blockDim.x;
    for (int idx = i; idx < N_NODES * DIM; idx += stride) {
        hp[idx]  = h[idx] + h_init[idx];
        agg[idx] = 0.0f;
    }
    for (int idx = i; idx < N_NODES * 2; idx += stride) posw[idx] = 0.0f;
    for (int idx = i; idx < N_NODES; idx += stride) deg[idx] = 0.0f;

    if (blockIdx.x == 0 && threadIdx.x == 0) {
        const int* e32 = (const int*)eidx;
        int f = 1;
        for (int k = 0; k < 64; ++k) {
            if (e32[2 * k + 1] != 0) { f = 0; break; }
        }
        flag[0] = f;
    }
}

// ---------------- Kernel 1: MFMA edge pipeline ----------------
// wave = 16-edge tile. Weights pre-packed in B-fragment layout (bf16) in LDS.
// mfma_f32_16x16x32_bf16 layouts: A: row=lane&15, k=8*(lane>>4)+j
//                                 B: col=lane&15, k=8*(lane>>4)+j
//                                 C/D: col=lane&15, row=(lane>>4)*4+reg
// d2 contribution (W_msg1 row 128) is applied via shfl+fma instead of a
// mostly-zero MFMA chunk: saves 4 MFMA + 4 ds_reads/tile and 4KB LDS,
// bringing LDS to ~50.2KB -> 3 blocks/CU (24 waves/CU).
__global__ __launch_bounds__(512, 6)
void k_edge(const float* __restrict__ hp, const float* __restrict__ pos,
            const void* __restrict__ eidx, const int* __restrict__ flag,
            const float* __restrict__ Wm1, const float* __restrict__ bm1,
            const float* __restrict__ Wm2, const float* __restrict__ bm2,
            const float* __restrict__ Wp1, const float* __restrict__ bp1,
            const float* __restrict__ Wp2, const float* __restrict__ bp2,
            float* __restrict__ agg, float* __restrict__ posw, float* __restrict__ deg)
{
    __shared__ short sW1[8192];      // 4 kk x 4 nt x 64 lanes x 8   (K=128)
    __shared__ short sW2[4096];      // 2 kk x 4 nt x 64 x 8
    __shared__ short sWp[4096];      // 2 kk x 4 nt x 64 x 8
    __shared__ float sB[260];        // bm1 | bm2 | bp1 | Wp2 | bp2
    __shared__ short sT[8][1024];    // per-wave 16x64 bf16 bounce tile (XOR-swizzled)

    // ---- stage weights in fragment order ----
    for (int i = threadIdx.x; i < 8192; i += 512) {
        int j = i & 7, lane = (i >> 3) & 63, nt = (i >> 9) & 3, kk = i >> 11;
        int k = kk * 32 + ((lane >> 4) << 3) + j;      // < 128
        int n = (nt << 4) + (lane & 15);
        sW1[i] = f2bf(Wm1[k * 64 + n]);
    }
    for (int i = threadIdx.x; i < 4096; i += 512) {
        int j = i & 7, lane = (i >> 3) & 63, nt = (i >> 9) & 3, kk = i >> 11;
        int k = kk * 32 + ((lane >> 4) << 3) + j;
        int n = (nt << 4) + (lane & 15);
        sW2[i] = f2bf(Wm2[k * 64 + n]);
        sWp[i] = f2bf(Wp1[k * 64 + n]);
    }
    if (threadIdx.x < 64) {
        sB[threadIdx.x]       = bm1[threadIdx.x];
        sB[64 + threadIdx.x]  = bm2[threadIdx.x];
        sB[128 + threadIdx.x] = bp1[threadIdx.x];
        sB[192 + threadIdx.x] = Wp2[threadIdx.x];
    }
    if (threadIdx.x == 0) sB[256] = bp2[0];
    __syncthreads();

    const int lane = threadIdx.x & 63;
    const int wv   = threadIdx.x >> 6;
    const int g    = lane >> 4;
    const int c    = lane & 15;
    short* tile = &sT[wv][0];

    const int is64 = flag[0];
    const int* e32 = (const int*)eidx;
    const long long* e64 = (const long long*)eidx;

    float bi1[4], bi2[4], bip[4], wp2r[4], w128f[4];
    #pragma unroll
    for (int nt = 0; nt < 4; ++nt) {
        bi1[nt]   = sB[nt * 16 + c];
        bi2[nt]   = sB[64 + nt * 16 + c];
        bip[nt]   = sB[128 + nt * 16 + c];
        wp2r[nt]  = sB[192 + nt * 16 + c];
        w128f[nt] = Wm1[128 * 64 + nt * 16 + c];   // d2 row of W_msg1
    }
    const float bp2v = sB[256];

    const int gw = blockIdx.x * 8 + wv;
    const int nw = gridDim.x * 8;

    // ---- prologue: prefetch first tile's indices + pos ----
    int srcC = 0, dstC = 0;
    float2 pdC = {0.f, 0.f}, psC = {0.f, 0.f};
    if (gw < NTILES) {
        int e0 = gw * 16 + c;
        if (is64) { srcC = (int)e64[e0]; dstC = (int)e64[N_EDGES + e0]; }
        else      { srcC = e32[e0];      dstC = e32[N_EDGES + e0]; }
        pdC = *(const float2*)(pos + (size_t)dstC * 2);
        psC = *(const float2*)(pos + (size_t)srcC * 2);
    }

    for (int t = gw; t < NTILES; t += nw) {
        const int src = srcC, dst = dstC;
        const float2 pd = pdC, ps = psC;
        const int tn = t + nw;

        float relx = pd.x - ps.x, rely = pd.y - ps.y;
        float d2 = relx * relx + rely * rely;

        const float* rowd = hp + (size_t)dst * 64 + g * 8;
        const float* rows = hp + (size_t)src * 64 + g * 8;

        // ---- layer 1: [16 x 128] @ [128 x 64] ----
        f32x4 acc[4];
        #pragma unroll
        for (int nt = 0; nt < 4; ++nt) acc[nt] = f32x4{0.f, 0.f, 0.f, 0.f};

        #pragma unroll
        for (int kk = 0; kk < 4; ++kk) {
            const float* p = (kk < 2) ? (rowd + kk * 32) : (rows + (kk - 2) * 32);
            float4 v0 = *(const float4*)p;
            float4 v1 = *(const float4*)(p + 4);
            short8 a;
            a[0] = f2bf(v0.x); a[1] = f2bf(v0.y); a[2] = f2bf(v0.z); a[3] = f2bf(v0.w);
            a[4] = f2bf(v1.x); a[5] = f2bf(v1.y); a[6] = f2bf(v1.z); a[7] = f2bf(v1.w);
            #pragma unroll
            for (int nt = 0; nt < 4; ++nt) {
                short8 b = *(const short8*)&sW1[(((kk << 2) + nt) << 9) + (lane << 3)];
                acc[nt] = __builtin_amdgcn_mfma_f32_16x16x32_bf16(a, b, acc[nt], 0, 0, 0);
            }
        }

        // ---- prefetch next tile's edge indices (latency hides under layer 2) ----
        if (tn < NTILES) {
            int en = tn * 16 + c;
            if (is64) { srcC = (int)e64[en]; dstC = (int)e64[N_EDGES + en]; }
            else      { srcC = e32[en];      dstC = e32[N_EDGES + en]; }
        }

        // d2 contribution + bias + silu -> t1 tile (bf16, XOR swizzle)
        float d2q[4];
        #pragma unroll
        for (int r = 0; r < 4; ++r) d2q[r] = __shfl(d2, g * 4 + r, 64);
        #pragma unroll
        for (int nt = 0; nt < 4; ++nt) {
            #pragma unroll
            for (int r = 0; r < 4; ++r) {
                float v = silu_f(fmaf(d2q[r], w128f[nt], acc[nt][r] + bi1[nt]));
                int row = g * 4 + r;
                int idx = ((row << 6) + (nt << 4) + c) ^ ((row & 7) << 3);
                tile[idx] = f2bf(v);
            }
        }
        asm volatile("s_waitcnt lgkmcnt(0)" ::: "memory");
        __builtin_amdgcn_sched_barrier(0);

        // ---- layer 2: t1[16x64] @ W2[64x64] ----
        short8 a20, a21;
        {
            int row = c;
            int b0 = ((row << 6) + (g << 3)) ^ ((row & 7) << 3);
            int b1 = ((row << 6) + 32 + (g << 3)) ^ ((row & 7) << 3);
            a20 = *(const short8*)&tile[b0];
            a21 = *(const short8*)&tile[b1];
        }
        f32x4 acc2[4];
        #pragma unroll
        for (int nt = 0; nt < 4; ++nt) acc2[nt] = f32x4{0.f, 0.f, 0.f, 0.f};
        #pragma unroll
        for (int nt = 0; nt < 4; ++nt) {
            short8 b0 = *(const short8*)&sW2[(nt << 9) + (lane << 3)];
            short8 b1 = *(const short8*)&sW2[((4 + nt) << 9) + (lane << 3)];
            acc2[nt] = __builtin_amdgcn_mfma_f32_16x16x32_bf16(a20, b0, acc2[nt], 0, 0, 0);
            acc2[nt] = __builtin_amdgcn_mfma_f32_16x16x32_bf16(a21, b1, acc2[nt], 0, 0, 0);
        }
        float mv[4][4];
        #pragma unroll
        for (int nt = 0; nt < 4; ++nt) {
            #pragma unroll
            for (int r = 0; r < 4; ++r) mv[nt][r] = silu_f(acc2[nt][r] + bi2[nt]);
        }

        // ---- prefetch next tile's pos (indices arrived during layer 2) ----
        if (tn < NTILES) {
            pdC = *(const float2*)(pos + (size_t)dstC * 2);
            psC = *(const float2*)(pos + (size_t)srcC * 2);
        }

        // write m tile for pos1 A-frags (t1 reads already consumed)
        asm volatile("s_waitcnt lgkmcnt(0)" ::: "memory");
        __builtin_amdgcn_sched_barrier(0);
        #pragma unroll
        for (int nt = 0; nt < 4; ++nt) {
            #pragma unroll
            for (int r = 0; r < 4; ++r) {
                int row = g * 4 + r;
                int idx = ((row << 6) + (nt << 4) + c) ^ ((row & 7) << 3);
                tile[idx] = f2bf(mv[nt][r]);
            }
        }
        // agg scatter: 16 contiguous lanes per instruction (64B bursts)
        #pragma unroll
        for (int r = 0; r < 4; ++r) {
            int q = g * 4 + r;
            int dstr = __shfl(dst, q, 64);
            float* basea = agg + (size_t)dstr * 64 + c;
            #pragma unroll
            for (int nt = 0; nt < 4; ++nt)
                atomicAdd(basea + nt * 16, mv[nt][r]);
        }
        asm volatile("s_waitcnt lgkmcnt(0)" ::: "memory");
        __builtin_amdgcn_sched_barrier(0);

        // ---- pos1: m[16x64] @ Wp1[64x64] ----
        short8 ap0, ap1;
        {
            int row = c;
            int b0 = ((row << 6) + (g << 3)) ^ ((row & 7) << 3);
            int b1 = ((row << 6) + 32 + (g << 3)) ^ ((row & 7) << 3);
            ap0 = *(const short8*)&tile[b0];
            ap1 = *(const short8*)&tile[b1];
        }
        f32x4 acc3[4];
        #pragma unroll
        for (int nt = 0; nt < 4; ++nt) acc3[nt] = f32x4{0.f, 0.f, 0.f, 0.f};
        #pragma unroll
        for (int nt = 0; nt < 4; ++nt) {
            short8 b0 = *(const short8*)&sWp[(nt << 9) + (lane << 3)];
            short8 b1 = *(const short8*)&sWp[((4 + nt) << 9) + (lane << 3)];
            acc3[nt] = __builtin_amdgcn_mfma_f32_16x16x32_bf16(ap0, b0, acc3[nt], 0, 0, 0);
            acc3[nt] = __builtin_amdgcn_mfma_f32_16x16x32_bf16(ap1, b1, acc3[nt], 0, 0, 0);
        }
        // ---- pos2 + scatter ----
        #pragma unroll
        for (int r = 0; r < 4; ++r) {
            float part = 0.f;
            #pragma unroll
            for (int nt = 0; nt < 4; ++nt)
                part = fmaf(silu_f(acc3[nt][r] + bip[nt]), wp2r[nt], part);
            part += __shfl_xor(part, 1, 64);
            part += __shfl_xor(part, 2, 64);
            part += __shfl_xor(part, 4, 64);
            part += __shfl_xor(part, 8, 64);
            float w = part + bp2v;
            int q = g * 4 + r;
            int dstr = __shfl(dst, q, 64);
            float rx = __shfl(relx, q, 64);
            float ry = __shfl(rely, q, 64);
            if (c == 0)      atomicAdd(posw + (size_t)dstr * 2 + 0, rx * w);
            else if (c == 1) atomicAdd(posw + (size_t)dstr * 2 + 1, ry * w);
            else if (c == 2) atomicAdd(deg + dstr, 1.0f);
        }
    }
}

// ---------------- Kernel 2: node MLP + outputs (f32 out) ----------------
__global__ __launch_bounds__(512, 2)
void k_node(const float* __restrict__ hp, const float* __restrict__ pos,
            const float* __restrict__ agg, const float* __restrict__ posw,
            const float* __restrict__ deg,
            const float* __restrict__ Wh1, const float* __restrict__ bh1,
            const float* __restrict__ Wh2, const float* __restrict__ bh2,
            float* __restrict__ out)
{
    __shared__ float sW1[128 * 64];
    __shared__ float sW2t[64 * 64];
    __shared__ float sB1[64];
    __shared__ float sB2[64];

    for (int i = threadIdx.x; i < 128 * 64; i += 512) sW1[i] = Wh1[i];
    for (int i = threadIdx.x; i < 64 * 64; i += 512) {
        int k = i >> 6, d = i & 63;
        sW2t[d * 64 + k] = Wh2[i];
    }
    if (threadIdx.x < 64) {
        sB1[threadIdx.x] = bh1[threadIdx.x];
        sB2[threadIdx.x] = bh2[threadIdx.x];
    }
    __syncthreads();

    const float4* W1v  = reinterpret_cast<const float4*>(sW1);
    const float4* W2tv = reinterpret_cast<const float4*>(sW2t);

    int tid = blockIdx.x * blockDim.x + threadIdx.x;
    int gstride = gridDim.x * blockDim.x;

    for (int n = tid; n < N_NODES; n += gstride) {
        const float4* rh = reinterpret_cast<const float4*>(hp + (size_t)n * DIM);
        const float4* ra = reinterpret_cast<const float4*>(agg + (size_t)n * DIM);

        float t[64];
        #pragma unroll
        for (int d = 0; d < 64; ++d) t[d] = sB1[d];

        for (int kc = 0; kc < 16; ++kc) {
            float4 ah = rh[kc];
            float4 aa = ra[kc];
            #pragma unroll
            for (int j = 0; j < 4; ++j) {
                float hj = (j == 0) ? ah.x : (j == 1) ? ah.y : (j == 2) ? ah.z : ah.w;
                float aj = (j == 0) ? aa.x : (j == 1) ? aa.y : (j == 2) ? aa.z : aa.w;
                int k = kc * 4 + j;
                #pragma unroll
                for (int dv = 0; dv < 16; ++dv) {
                    float4 w1 = W1v[k * 16 + dv];
                    t[dv * 4 + 0] = fmaf(hj, w1.x, t[dv * 4 + 0]);
                    t[dv * 4 + 1] = fmaf(hj, w1.y, t[dv * 4 + 1]);
                    t[dv * 4 + 2] = fmaf(hj, w1.z, t[dv * 4 + 2]);
                    t[dv * 4 + 3] = fmaf(hj, w1.w, t[dv * 4 + 3]);
                    float4 w2 = W1v[(64 + k) * 16 + dv];
                    t[dv * 4 + 0] = fmaf(aj, w2.x, t[dv * 4 + 0]);
                    t[dv * 4 + 1] = fmaf(aj, w2.y, t[dv * 4 + 1]);
                    t[dv * 4 + 2] = fmaf(aj, w2.z, t[dv * 4 + 2]);
                    t[dv * 4 + 3] = fmaf(aj, w2.w, t[dv * 4 + 3]);
                }
            }
        }
        #pragma unroll
        for (int d = 0; d < 64; ++d) t[d] = silu_f(t[d]);

        for (int kd = 0; kd < 64; ++kd) {
            float s = sB2[kd];
            #pragma unroll
            for (int kv = 0; kv < 16; ++kv) {
                float4 wv = W2tv[kd * 16 + kv];
                s = fmaf(t[kv * 4 + 0], wv.x, s);
                s = fmaf(t[kv * 4 + 1], wv.y, s);
                s = fmaf(t[kv * 4 + 2], wv.z, s);
                s = fmaf(t[kv * 4 + 3], wv.w, s);
            }
            out[(size_t)n * DIM + kd] = hp[(size_t)n * DIM + kd] + s;
        }

        float dg = fmaxf(deg[n], 1.0f);
        float inv = __builtin_amdgcn_rcpf(dg);
        float2 po = *reinterpret_cast<const float2*>(pos + (size_t)n * 2);
        float2 pw = *reinterpret_cast<const float2*>(posw + (size_t)n * 2);
        float2 res;
        res.x = po.x + pw.x * inv;
        res.y = po.y + pw.y * inv;
        *reinterpret_cast<float2*>(out + (size_t)N_NODES * DIM + (size_t)n * 2) = res;
    }
}

extern "C" void kernel_launch(void* const* d_in, const int* in_sizes, int n_in,
                              void* d_out, int out_size, void* d_ws, size_t ws_size,
                              hipStream_t stream) {
    const float* h      = (const float*)d_in[0];
    const float* pos    = (const float*)d_in[1];
    const float* h_init = (const float*)d_in[2];
    const float* Wm1    = (const float*)d_in[3];
    const float* bm1    = (const float*)d_in[4];
    const float* Wm2    = (const float*)d_in[5];
    const float* bm2    = (const float*)d_in[6];
    const float* Wp1    = (const float*)d_in[7];
    const float* bp1    = (const float*)d_in[8];
    const float* Wp2    = (const float*)d_in[9];
    const float* bp2    = (const float*)d_in[10];
    const float* Wh1    = (const float*)d_in[11];
    const float* bh1    = (const float*)d_in[12];
    const float* Wh2    = (const float*)d_in[13];
    const float* bh2    = (const float*)d_in[14];
    const void*  eidx   = (const void*)d_in[15];
    float* out = (float*)d_out;

    float* ws   = (float*)d_ws;
    float* hp   = ws;                               // N*64
    float* agg  = ws + (size_t)N_NODES * DIM;       // N*64
    float* posw = agg + (size_t)N_NODES * DIM;      // N*2
    float* deg  = posw + (size_t)N_NODES * 2;       // N
    int*   flag = (int*)(deg + N_NODES);            // 1

    k_init<<<2048, 256, 0, stream>>>(h, h_init, hp, agg, posw, deg, eidx, flag);
    k_edge<<<768, 512, 0, stream>>>(hp, pos, eidx, flag, Wm1, bm1, Wm2, bm2,
                                    Wp1, bp1, Wp2, bp2, agg, posw, deg);
    k_node<<<98, 512, 0, stream>>>(hp, pos, agg, posw, deg, Wh1, bh1, Wh2, bh2, out);
}

// Round 6
// 361.474 us; speedup vs baseline: 1.1358x; 1.1358x over previous
//
#include <hip/hip_runtime.h>
#include <hip/hip_bf16.h>

#define N_NODES 50000
#define DIM 64
#define N_EDGES 800000
#define NTILES (N_EDGES / 16)
#define NODE_TILES (N_NODES / 16)   // 3125 exactly

typedef short short8 __attribute__((ext_vector_type(8)));
typedef float f32x4 __attribute__((ext_vector_type(4)));

__device__ __forceinline__ float silu_f(float x) {
    return x * __builtin_amdgcn_rcpf(1.0f + __expf(-x));
}
// f32 -> bf16 round-to-nearest-even
__device__ __forceinline__ short f2bf(float f) {
    unsigned u = __builtin_bit_cast(unsigned, f);
    u += 0x7FFFu + ((u >> 16) & 1u);
    return (short)(u >> 16);
}

// ---------------- Kernel 0: hpb = bf16(h + h_init); zero accs; eidx -> int32 ----------------
__global__ void k_init(const float* __restrict__ h, const float* __restrict__ h_init,
                       short* __restrict__ hpb, float* __restrict__ agg,
                       float* __restrict__ posw, float* __restrict__ deg,
                       const void* __restrict__ eidx, int* __restrict__ eidx32) {
    __shared__ int sIs64;
    if (threadIdx.x == 0) {
        // int64 little-endian => odd int32 words all 0 (ids < 50000)
        const int* e = (const int*)eidx;
        int f = 1;
        for (int k = 0; k < 64; ++k) if (e[2 * k + 1] != 0) { f = 0; break; }
        sIs64 = f;
    }
    __syncthreads();
    const int is64 = sIs64;

    int i = blockIdx.x * blockDim.x + threadIdx.x;
    int stride = gridDim.x * blockDim.x;
    for (int idx = i; idx < N_NODES * DIM; idx += stride) {
        hpb[idx] = f2bf(h[idx] + h_init[idx]);
        agg[idx] = 0.0f;
    }
    for (int idx = i; idx < N_NODES * 2; idx += stride) posw[idx] = 0.0f;
    for (int idx = i; idx < N_NODES; idx += stride) deg[idx] = 0.0f;

    const long long* e64 = (const long long*)eidx;
    const int* e32 = (const int*)eidx;
    for (int idx = i; idx < 2 * N_EDGES; idx += stride)
        eidx32[idx] = is64 ? (int)e64[idx] : e32[idx];
}

// ---------------- Kernel 1: MFMA edge pipeline with cross-tile prefetch ----------------
// wave = 16-edge tile. Weights in B-fragment layout (bf16) in LDS.
// A: row=lane&15, k=8*(lane>>4)+j | B: col=lane&15, k=8*(lane>>4)+j
// C/D: col=lane&15, row=(lane>>4)*4+reg
__global__ __launch_bounds__(512, 6)
void k_edge(const short* __restrict__ hpb, const float* __restrict__ pos,
            const int* __restrict__ ei,
            const float* __restrict__ Wm1, const float* __restrict__ bm1,
            const float* __restrict__ Wm2, const float* __restrict__ bm2,
            const float* __restrict__ Wp1, const float* __restrict__ bp1,
            const float* __restrict__ Wp2, const float* __restrict__ bp2,
            float* __restrict__ agg, float* __restrict__ posw, float* __restrict__ deg)
{
    __shared__ short sW1[8192];      // 4 kk x 4 nt x 64 lanes x 8  (K=128)
    __shared__ short sW2[4096];      // 2 kk x 4 nt
    __shared__ short sWp[4096];      // 2 kk x 4 nt
    __shared__ short sT[8][1024];    // per-wave 16x64 bf16 bounce tile (XOR-swizzled)

    for (int i = threadIdx.x; i < 8192; i += 512) {
        int j = i & 7, lane = (i >> 3) & 63, nt = (i >> 9) & 3, kk = i >> 11;
        int k = kk * 32 + ((lane >> 4) << 3) + j;
        int n = (nt << 4) + (lane & 15);
        sW1[i] = f2bf(Wm1[k * 64 + n]);
    }
    for (int i = threadIdx.x; i < 4096; i += 512) {
        int j = i & 7, lane = (i >> 3) & 63, nt = (i >> 9) & 3, kk = i >> 11;
        int k = kk * 32 + ((lane >> 4) << 3) + j;
        int n = (nt << 4) + (lane & 15);
        sW2[i] = f2bf(Wm2[k * 64 + n]);
        sWp[i] = f2bf(Wp1[k * 64 + n]);
    }
    __syncthreads();

    const int lane = threadIdx.x & 63;
    const int wv   = threadIdx.x >> 6;
    const int g    = lane >> 4;
    const int c    = lane & 15;
    short* tile = &sT[wv][0];

    // per-lane bias/weight registers (small global reads, L2-cached)
    float bi1[4], bi2[4], bip[4], wp2r[4], w128f[4];
    #pragma unroll
    for (int nt = 0; nt < 4; ++nt) {
        bi1[nt]   = bm1[nt * 16 + c];
        bi2[nt]   = bm2[nt * 16 + c];
        bip[nt]   = bp1[nt * 16 + c];
        wp2r[nt]  = Wp2[nt * 16 + c];
        w128f[nt] = Wm1[128 * 64 + nt * 16 + c];   // d2 row of W_msg1
    }
    const float bp2v = bp2[0];

    const int gw = blockIdx.x * 8 + wv;
    const int nw = gridDim.x * 8;

    // ---- prologue: tile t indices+pos+frags; tile t+nw indices ----
    int s0 = 0, d0 = 0, s1 = 0, d1 = 0;
    float2 pd0 = {0.f, 0.f}, ps0 = {0.f, 0.f};
    short8 f0, f1, f2, f3;
    if (gw < NTILES) {
        int e = gw * 16 + c;
        s0 = ei[e]; d0 = ei[N_EDGES + e];
        pd0 = *(const float2*)(pos + (size_t)d0 * 2);
        ps0 = *(const float2*)(pos + (size_t)s0 * 2);
        f0 = *(const short8*)&hpb[(size_t)d0 * 64 + g * 8];
        f1 = *(const short8*)&hpb[(size_t)d0 * 64 + 32 + g * 8];
        f2 = *(const short8*)&hpb[(size_t)s0 * 64 + g * 8];
        f3 = *(const short8*)&hpb[(size_t)s0 * 64 + 32 + g * 8];
    }
    if (gw + nw < NTILES) {
        int e = (gw + nw) * 16 + c;
        s1 = ei[e]; d1 = ei[N_EDGES + e];
    }

    for (int t = gw; t < NTILES; t += nw) {
        const bool hasN  = (t + nw) < NTILES;
        const bool hasNN = (t + 2 * nw) < NTILES;

        float relx = pd0.x - ps0.x, rely = pd0.y - ps0.y;
        float dist2 = relx * relx + rely * rely;

        // ---- layer 1: [16 x 128] @ [128 x 64] (A-frags prefetched) ----
        f32x4 acc[4];
        #pragma unroll
        for (int nt = 0; nt < 4; ++nt) acc[nt] = f32x4{0.f, 0.f, 0.f, 0.f};
        #pragma unroll
        for (int nt = 0; nt < 4; ++nt) {
            short8 b0 = *(const short8*)&sW1[((0 * 4 + nt) << 9) + (lane << 3)];
            short8 b1 = *(const short8*)&sW1[((1 * 4 + nt) << 9) + (lane << 3)];
            short8 b2 = *(const short8*)&sW1[((2 * 4 + nt) << 9) + (lane << 3)];
            short8 b3 = *(const short8*)&sW1[((3 * 4 + nt) << 9) + (lane << 3)];
            acc[nt] = __builtin_amdgcn_mfma_f32_16x16x32_bf16(f0, b0, acc[nt], 0, 0, 0);
            acc[nt] = __builtin_amdgcn_mfma_f32_16x16x32_bf16(f1, b1, acc[nt], 0, 0, 0);
            acc[nt] = __builtin_amdgcn_mfma_f32_16x16x32_bf16(f2, b2, acc[nt], 0, 0, 0);
            acc[nt] = __builtin_amdgcn_mfma_f32_16x16x32_bf16(f3, b3, acc[nt], 0, 0, 0);
        }

        // ---- prefetch tile t+nw pos+frags (idx already here), idx for t+2nw ----
        short8 g0, g1, g2, g3;
        float2 pd1, ps1;
        if (hasN) {
            pd1 = *(const float2*)(pos + (size_t)d1 * 2);
            ps1 = *(const float2*)(pos + (size_t)s1 * 2);
            g0 = *(const short8*)&hpb[(size_t)d1 * 64 + g * 8];
            g1 = *(const short8*)&hpb[(size_t)d1 * 64 + 32 + g * 8];
            g2 = *(const short8*)&hpb[(size_t)s1 * 64 + g * 8];
            g3 = *(const short8*)&hpb[(size_t)s1 * 64 + 32 + g * 8];
        }
        int s2 = 0, d2i = 0;
        if (hasNN) {
            int e = (t + 2 * nw) * 16 + c;
            s2 = ei[e]; d2i = ei[N_EDGES + e];
        }

        // d2 contribution + bias + silu -> t1 tile (bf16, XOR swizzle)
        float d2q[4];
        #pragma unroll
        for (int r = 0; r < 4; ++r) d2q[r] = __shfl(dist2, g * 4 + r, 64);
        #pragma unroll
        for (int nt = 0; nt < 4; ++nt) {
            #pragma unroll
            for (int r = 0; r < 4; ++r) {
                float v = silu_f(fmaf(d2q[r], w128f[nt], acc[nt][r] + bi1[nt]));
                int row = g * 4 + r;
                int idx = ((row << 6) + (nt << 4) + c) ^ ((row & 7) << 3);
                tile[idx] = f2bf(v);
            }
        }
        asm volatile("s_waitcnt lgkmcnt(0)" ::: "memory");
        __builtin_amdgcn_sched_barrier(0);

        // ---- layer 2: t1[16x64] @ W2[64x64] ----
        short8 a20, a21;
        {
            int row = c;
            int b0 = ((row << 6) + (g << 3)) ^ ((row & 7) << 3);
            int b1 = ((row << 6) + 32 + (g << 3)) ^ ((row & 7) << 3);
            a20 = *(const short8*)&tile[b0];
            a21 = *(const short8*)&tile[b1];
        }
        f32x4 acc2[4];
        #pragma unroll
        for (int nt = 0; nt < 4; ++nt) acc2[nt] = f32x4{0.f, 0.f, 0.f, 0.f};
        #pragma unroll
        for (int nt = 0; nt < 4; ++nt) {
            short8 b0 = *(const short8*)&sW2[(nt << 9) + (lane << 3)];
            short8 b1 = *(const short8*)&sW2[((4 + nt) << 9) + (lane << 3)];
            acc2[nt] = __builtin_amdgcn_mfma_f32_16x16x32_bf16(a20, b0, acc2[nt], 0, 0, 0);
            acc2[nt] = __builtin_amdgcn_mfma_f32_16x16x32_bf16(a21, b1, acc2[nt], 0, 0, 0);
        }
        float mv[4][4];
        #pragma unroll
        for (int nt = 0; nt < 4; ++nt) {
            #pragma unroll
            for (int r = 0; r < 4; ++r) mv[nt][r] = silu_f(acc2[nt][r] + bi2[nt]);
        }

        // write m tile for pos1 A-frags (t1 reads already consumed)
        asm volatile("s_waitcnt lgkmcnt(0)" ::: "memory");
        __builtin_amdgcn_sched_barrier(0);
        #pragma unroll
        for (int nt = 0; nt < 4; ++nt) {
            #pragma unroll
            for (int r = 0; r < 4; ++r) {
                int row = g * 4 + r;
                int idx = ((row << 6) + (nt << 4) + c) ^ ((row & 7) << 3);
                tile[idx] = f2bf(mv[nt][r]);
            }
        }
        // agg scatter: 16 contiguous lanes per instruction (64B bursts)
        #pragma unroll
        for (int r = 0; r < 4; ++r) {
            int q = g * 4 + r;
            int dstr = __shfl(d0, q, 64);
            float* basea = agg + (size_t)dstr * 64 + c;
            #pragma unroll
            for (int nt = 0; nt < 4; ++nt)
                atomicAdd(basea + nt * 16, mv[nt][r]);
        }
        asm volatile("s_waitcnt lgkmcnt(0)" ::: "memory");
        __builtin_amdgcn_sched_barrier(0);

        // ---- pos1: m[16x64] @ Wp1[64x64] ----
        short8 ap0, ap1;
        {
            int row = c;
            int b0 = ((row << 6) + (g << 3)) ^ ((row & 7) << 3);
            int b1 = ((row << 6) + 32 + (g << 3)) ^ ((row & 7) << 3);
            ap0 = *(const short8*)&tile[b0];
            ap1 = *(const short8*)&tile[b1];
        }
        f32x4 acc3[4];
        #pragma unroll
        for (int nt = 0; nt < 4; ++nt) acc3[nt] = f32x4{0.f, 0.f, 0.f, 0.f};
        #pragma unroll
        for (int nt = 0; nt < 4; ++nt) {
            short8 b0 = *(const short8*)&sWp[(nt << 9) + (lane << 3)];
            short8 b1 = *(const short8*)&sWp[((4 + nt) << 9) + (lane << 3)];
            acc3[nt] = __builtin_amdgcn_mfma_f32_16x16x32_bf16(ap0, b0, acc3[nt], 0, 0, 0);
            acc3[nt] = __builtin_amdgcn_mfma_f32_16x16x32_bf16(ap1, b1, acc3[nt], 0, 0, 0);
        }
        // ---- pos2 + scatter ----
        #pragma unroll
        for (int r = 0; r < 4; ++r) {
            float part = 0.f;
            #pragma unroll
            for (int nt = 0; nt < 4; ++nt)
                part = fmaf(silu_f(acc3[nt][r] + bip[nt]), wp2r[nt], part);
            part += __shfl_xor(part, 1, 64);
            part += __shfl_xor(part, 2, 64);
            part += __shfl_xor(part, 4, 64);
            part += __shfl_xor(part, 8, 64);
            float w = part + bp2v;
            int q = g * 4 + r;
            int dstr = __shfl(d0, q, 64);
            float rx = __shfl(relx, q, 64);
            float ry = __shfl(rely, q, 64);
            if (c == 0)      atomicAdd(posw + (size_t)dstr * 2 + 0, rx * w);
            else if (c == 1) atomicAdd(posw + (size_t)dstr * 2 + 1, ry * w);
            else if (c == 2) atomicAdd(deg + dstr, 1.0f);
        }

        // ---- rotate pipeline registers ----
        s0 = s1; d0 = d1; pd0 = pd1; ps0 = ps1;
        f0 = g0; f1 = g1; f2 = g2; f3 = g3;
        s1 = s2; d1 = d2i;
    }
}

// ---------------- Kernel 2: node MLP via MFMA + outputs (f32) ----------------
// wave = 16-node tile; A = [bf16(h+h_init) | bf16(agg)], K=128.
__global__ __launch_bounds__(512)
void k_node(const float* __restrict__ h, const float* __restrict__ h_init,
            const short* __restrict__ hpb, const float* __restrict__ pos,
            const float* __restrict__ agg, const float* __restrict__ posw,
            const float* __restrict__ deg,
            const float* __restrict__ Wh1, const float* __restrict__ bh1,
            const float* __restrict__ Wh2, const float* __restrict__ bh2,
            float* __restrict__ out)
{
    __shared__ short sW1[8192];      // 4 kk x 4 nt x 64 x 8  (K=128)
    __shared__ short sW2[4096];      // 2 kk x 4 nt
    __shared__ short sT[8][1024];

    for (int i = threadIdx.x; i < 8192; i += 512) {
        int j = i & 7, lane = (i >> 3) & 63, nt = (i >> 9) & 3, kk = i >> 11;
        int k = kk * 32 + ((lane >> 4) << 3) + j;
        int n = (nt << 4) + (lane & 15);
        sW1[i] = f2bf(Wh1[k * 64 + n]);
    }
    for (int i = threadIdx.x; i < 4096; i += 512) {
        int j = i & 7, lane = (i >> 3) & 63, nt = (i >> 9) & 3, kk = i >> 11;
        int k = kk * 32 + ((lane >> 4) << 3) + j;
        int n = (nt << 4) + (lane & 15);
        sW2[i] = f2bf(Wh2[k * 64 + n]);
    }
    __syncthreads();

    const int lane = threadIdx.x & 63;
    const int wv   = threadIdx.x >> 6;
    const int g    = lane >> 4;
    const int c    = lane & 15;
    short* tile = &sT[wv][0];

    const int tl = blockIdx.x * 8 + wv;
    if (tl >= NODE_TILES) return;
    const int tb = tl * 16;

    float bi1[4], bi2[4];
    #pragma unroll
    for (int nt = 0; nt < 4; ++nt) {
        bi1[nt] = bh1[nt * 16 + c];
        bi2[nt] = bh2[nt * 16 + c];
    }

    const int node = tb + c;   // A-frag row = lane&15
    short8 a0 = *(const short8*)&hpb[(size_t)node * 64 + g * 8];
    short8 a1 = *(const short8*)&hpb[(size_t)node * 64 + 32 + g * 8];
    short8 a2, a3;
    {
        const float* ar = agg + (size_t)node * 64;
        float4 u0 = *(const float4*)(ar + g * 8);
        float4 u1 = *(const float4*)(ar + g * 8 + 4);
        a2[0] = f2bf(u0.x); a2[1] = f2bf(u0.y); a2[2] = f2bf(u0.z); a2[3] = f2bf(u0.w);
        a2[4] = f2bf(u1.x); a2[5] = f2bf(u1.y); a2[6] = f2bf(u1.z); a2[7] = f2bf(u1.w);
        float4 w0 = *(const float4*)(ar + 32 + g * 8);
        float4 w1 = *(const float4*)(ar + 32 + g * 8 + 4);
        a3[0] = f2bf(w0.x); a3[1] = f2bf(w0.y); a3[2] = f2bf(w0.z); a3[3] = f2bf(w0.w);
        a3[4] = f2bf(w1.x); a3[5] = f2bf(w1.y); a3[6] = f2bf(w1.z); a3[7] = f2bf(w1.w);
    }

    f32x4 acc[4];
    #pragma unroll
    for (int nt = 0; nt < 4; ++nt) acc[nt] = f32x4{0.f, 0.f, 0.f, 0.f};
    #pragma unroll
    for (int nt = 0; nt < 4; ++nt) {
        short8 b0 = *(const short8*)&sW1[((0 * 4 + nt) << 9) + (lane << 3)];
        short8 b1 = *(const short8*)&sW1[((1 * 4 + nt) << 9) + (lane << 3)];
        short8 b2 = *(const short8*)&sW1[((2 * 4 + nt) << 9) + (lane << 3)];
        short8 b3 = *(const short8*)&sW1[((3 * 4 + nt) << 9) + (lane << 3)];
        acc[nt] = __builtin_amdgcn_mfma_f32_16x16x32_bf16(a0, b0, acc[nt], 0, 0, 0);
        acc[nt] = __builtin_amdgcn_mfma_f32_16x16x32_bf16(a1, b1, acc[nt], 0, 0, 0);
        acc[nt] = __builtin_amdgcn_mfma_f32_16x16x32_bf16(a2, b2, acc[nt], 0, 0, 0);
        acc[nt] = __builtin_amdgcn_mfma_f32_16x16x32_bf16(a3, b3, acc[nt], 0, 0, 0);
    }
    // silu -> tile
    #pragma unroll
    for (int nt = 0; nt < 4; ++nt) {
        #pragma unroll
        for (int r = 0; r < 4; ++r) {
            float v = silu_f(acc[nt][r] + bi1[nt]);
            int row = g * 4 + r;
            int idx = ((row << 6) + (nt << 4) + c) ^ ((row & 7) << 3);
            tile[idx] = f2bf(v);
        }
    }
    asm volatile("s_waitcnt lgkmcnt(0)" ::: "memory");
    __builtin_amdgcn_sched_barrier(0);

    // layer 2
    short8 a20, a21;
    {
        int row = c;
        int b0 = ((row << 6) + (g << 3)) ^ ((row & 7) << 3);
        int b1 = ((row << 6) + 32 + (g << 3)) ^ ((row & 7) << 3);
        a20 = *(const short8*)&tile[b0];
        a21 = *(const short8*)&tile[b1];
    }
    f32x4 acc2[4];
    #pragma unroll
    for (int nt = 0; nt < 4; ++nt) acc2[nt] = f32x4{0.f, 0.f, 0.f, 0.f};
    #pragma unroll
    for (int nt = 0; nt < 4; ++nt) {
        short8 b0 = *(const short8*)&sW2[(nt << 9) + (lane << 3)];
        short8 b1 = *(const short8*)&sW2[((4 + nt) << 9) + (lane << 3)];
        acc2[nt] = __builtin_amdgcn_mfma_f32_16x16x32_bf16(a20, b0, acc2[nt], 0, 0, 0);
        acc2[nt] = __builtin_amdgcn_mfma_f32_16x16x32_bf16(a21, b1, acc2[nt], 0, 0, 0);
    }
    // epilogue: out_h = (h + h_init) + s   (residual in f32)
    #pragma unroll
    for (int r = 0; r < 4; ++r) {
        int q = g * 4 + r;
        #pragma unroll
        for (int nt = 0; nt < 4; ++nt) {
            size_t idx = (size_t)(tb + q) * 64 + nt * 16 + c;
            out[idx] = h[idx] + h_init[idx] + acc2[nt][r] + bi2[nt];
        }
    }
    // pos output: lanes 0..15 handle the tile's 16 nodes
    if (lane < 16) {
        int n2 = tb + lane;
        float dg = fmaxf(deg[n2], 1.0f);
        float inv = __builtin_amdgcn_rcpf(dg);
        float2 po = *(const float2*)(pos + (size_t)n2 * 2);
        float2 pw = *(const float2*)(posw + (size_t)n2 * 2);
        float2 res;
        res.x = po.x + pw.x * inv;
        res.y = po.y + pw.y * inv;
        *(float2*)(out + (size_t)N_NODES * DIM + (size_t)n2 * 2) = res;
    }
}

extern "C" void kernel_launch(void* const* d_in, const int* in_sizes, int n_in,
                              void* d_out, int out_size, void* d_ws, size_t ws_size,
                              hipStream_t stream) {
    const float* h      = (const float*)d_in[0];
    const float* pos    = (const float*)d_in[1];
    const float* h_init = (const float*)d_in[2];
    const float* Wm1    = (const float*)d_in[3];
    const float* bm1    = (const float*)d_in[4];
    const float* Wm2    = (const float*)d_in[5];
    const float* bm2    = (const float*)d_in[6];
    const float* Wp1    = (const float*)d_in[7];
    const float* bp1    = (const float*)d_in[8];
    const float* Wp2    = (const float*)d_in[9];
    const float* bp2    = (const float*)d_in[10];
    const float* Wh1    = (const float*)d_in[11];
    const float* bh1    = (const float*)d_in[12];
    const float* Wh2    = (const float*)d_in[13];
    const float* bh2    = (const float*)d_in[14];
    const void*  eidx   = (const void*)d_in[15];
    float* out = (float*)d_out;

    float* ws     = (float*)d_ws;
    float* agg    = ws;                                   // N*64 f32
    float* posw   = agg + (size_t)N_NODES * DIM;          // N*2
    float* deg    = posw + (size_t)N_NODES * 2;           // N
    short* hpb    = (short*)(deg + N_NODES);              // N*64 bf16
    int*   eidx32 = (int*)(hpb + (size_t)N_NODES * DIM);  // 2E int32

    k_init<<<2048, 256, 0, stream>>>(h, h_init, hpb, agg, posw, deg, eidx, eidx32);
    k_edge<<<768, 512, 0, stream>>>(hpb, pos, eidx32, Wm1, bm1, Wm2, bm2,
                                    Wp1, bp1, Wp2, bp2, agg, posw, deg);
    k_node<<<(NODE_TILES + 7) / 8, 512, 0, stream>>>(h, h_init, hpb, pos, agg, posw, deg,
                                                     Wh1, bh1, Wh2, bh2, out);
}

// Round 7
// 222.679 us; speedup vs baseline: 1.8438x; 1.6233x over previous
//
#include <hip/hip_runtime.h>
#include <hip/hip_bf16.h>

#define N_NODES 50000
#define DIM 64
#define N_EDGES 800000
#define NTILES (N_EDGES / 16)
#define NODE_TILES (N_NODES / 16)   // 3125 exactly

typedef short short8 __attribute__((ext_vector_type(8)));
typedef float f32x4 __attribute__((ext_vector_type(4)));

__device__ __forceinline__ float silu_f(float x) {
    return x * __builtin_amdgcn_rcpf(1.0f + __expf(-x));
}
// f32 -> bf16 round-to-nearest-even
__device__ __forceinline__ short f2bf(float f) {
    unsigned u = __builtin_bit_cast(unsigned, f);
    u += 0x7FFFu + ((u >> 16) & 1u);
    return (short)(u >> 16);
}
// packed bf16x2 atomic add (no return) — halves agg atomic traffic
__device__ __forceinline__ void atom_pk_bf16(void* addr, unsigned data) {
    asm volatile("global_atomic_pk_add_bf16 %0, %1, off"
                 :: "v"((unsigned long long)(uintptr_t)addr), "v"(data) : "memory");
}

// ---------------- Kernel 0: hpb = bf16(h + h_init); zero accs; eidx -> int32 ----------------
__global__ void k_init(const float* __restrict__ h, const float* __restrict__ h_init,
                       short* __restrict__ hpb, int* __restrict__ aggz,
                       float* __restrict__ posw3,
                       const void* __restrict__ eidx, int* __restrict__ eidx32) {
    __shared__ int sIs64;
    if (threadIdx.x == 0) {
        const int* e = (const int*)eidx;
        int f = 1;
        for (int k = 0; k < 64; ++k) if (e[2 * k + 1] != 0) { f = 0; break; }
        sIs64 = f;
    }
    __syncthreads();
    const int is64 = sIs64;

    int i = blockIdx.x * blockDim.x + threadIdx.x;
    int stride = gridDim.x * blockDim.x;
    for (int idx = i; idx < N_NODES * DIM; idx += stride)
        hpb[idx] = f2bf(h[idx] + h_init[idx]);
    for (int idx = i; idx < N_NODES * 32; idx += stride) aggz[idx] = 0;   // bf16 agg, as ints
    for (int idx = i; idx < N_NODES * 4; idx += stride) posw3[idx] = 0.0f;

    const long long* e64 = (const long long*)eidx;
    const int* e32 = (const int*)eidx;
    for (int idx = i; idx < 2 * N_EDGES; idx += stride)
        eidx32[idx] = is64 ? (int)e64[idx] : e32[idx];
}

// ---------------- Kernel 1: MFMA edge pipeline, packed-atomic scatter ----------------
// wave = 16-edge tile. Weights in B-fragment layout (bf16) in LDS.
// A: row=lane&15, k=8*(lane>>4)+j | B: col=lane&15, k=8*(lane>>4)+j
// C/D: col=lane&15, row=(lane>>4)*4+reg
// agg stored bf16 in interleaved order sigma(nt,c)=2c+(nt&1)+32*(nt>>1) so
// (mv[0],mv[1]) and (mv[2],mv[3]) are memory-adjacent pairs for pk_add_bf16.
__global__ __launch_bounds__(512, 6)
void k_edge(const short* __restrict__ hpb, const float* __restrict__ pos,
            const int* __restrict__ ei,
            const float* __restrict__ Wm1, const float* __restrict__ bm1,
            const float* __restrict__ Wm2, const float* __restrict__ bm2,
            const float* __restrict__ Wp1, const float* __restrict__ bp1,
            const float* __restrict__ Wp2, const float* __restrict__ bp2,
            short* __restrict__ aggb, float* __restrict__ posw3)
{
    __shared__ short sW1[8192];      // 4 kk x 4 nt x 64 lanes x 8  (K=128)
    __shared__ short sW2[4096];
    __shared__ short sWp[4096];
    __shared__ short sT[8][1024];    // per-wave 16x64 bf16 bounce tile (XOR-swizzled)

    for (int i = threadIdx.x; i < 8192; i += 512) {
        int j = i & 7, lane = (i >> 3) & 63, nt = (i >> 9) & 3, kk = i >> 11;
        int k = kk * 32 + ((lane >> 4) << 3) + j;
        int n = (nt << 4) + (lane & 15);
        sW1[i] = f2bf(Wm1[k * 64 + n]);
    }
    for (int i = threadIdx.x; i < 4096; i += 512) {
        int j = i & 7, lane = (i >> 3) & 63, nt = (i >> 9) & 3, kk = i >> 11;
        int k = kk * 32 + ((lane >> 4) << 3) + j;
        int n = (nt << 4) + (lane & 15);
        sW2[i] = f2bf(Wm2[k * 64 + n]);
        sWp[i] = f2bf(Wp1[k * 64 + n]);
    }
    __syncthreads();

    const int lane = threadIdx.x & 63;
    const int wv   = threadIdx.x >> 6;
    const int g    = lane >> 4;
    const int c    = lane & 15;
    short* tile = &sT[wv][0];

    float bi1[4], bi2[4], bip[4], wp2r[4], w128f[4];
    #pragma unroll
    for (int nt = 0; nt < 4; ++nt) {
        bi1[nt]   = bm1[nt * 16 + c];
        bi2[nt]   = bm2[nt * 16 + c];
        bip[nt]   = bp1[nt * 16 + c];
        wp2r[nt]  = Wp2[nt * 16 + c];
        w128f[nt] = Wm1[128 * 64 + nt * 16 + c];   // d2 row of W_msg1
    }
    const float bp2v = bp2[0];

    const int gw = blockIdx.x * 8 + wv;
    const int nw = gridDim.x * 8;

    // ---- prologue: tile t indices+pos+frags; tile t+nw indices ----
    int s0 = 0, d0 = 0, s1 = 0, d1 = 0;
    float2 pd0 = {0.f, 0.f}, ps0 = {0.f, 0.f};
    short8 f0, f1, f2, f3;
    if (gw < NTILES) {
        int e = gw * 16 + c;
        s0 = ei[e]; d0 = ei[N_EDGES + e];
        pd0 = *(const float2*)(pos + (size_t)d0 * 2);
        ps0 = *(const float2*)(pos + (size_t)s0 * 2);
        f0 = *(const short8*)&hpb[(size_t)d0 * 64 + g * 8];
        f1 = *(const short8*)&hpb[(size_t)d0 * 64 + 32 + g * 8];
        f2 = *(const short8*)&hpb[(size_t)s0 * 64 + g * 8];
        f3 = *(const short8*)&hpb[(size_t)s0 * 64 + 32 + g * 8];
    }
    if (gw + nw < NTILES) {
        int e = (gw + nw) * 16 + c;
        s1 = ei[e]; d1 = ei[N_EDGES + e];
    }

    for (int t = gw; t < NTILES; t += nw) {
        const bool hasN  = (t + nw) < NTILES;
        const bool hasNN = (t + 2 * nw) < NTILES;

        float relx = pd0.x - ps0.x, rely = pd0.y - ps0.y;
        float dist2 = relx * relx + rely * rely;

        // ---- layer 1: [16 x 128] @ [128 x 64] (A-frags prefetched) ----
        f32x4 acc[4];
        #pragma unroll
        for (int nt = 0; nt < 4; ++nt) acc[nt] = f32x4{0.f, 0.f, 0.f, 0.f};
        #pragma unroll
        for (int nt = 0; nt < 4; ++nt) {
            short8 b0 = *(const short8*)&sW1[((0 * 4 + nt) << 9) + (lane << 3)];
            short8 b1 = *(const short8*)&sW1[((1 * 4 + nt) << 9) + (lane << 3)];
            short8 b2 = *(const short8*)&sW1[((2 * 4 + nt) << 9) + (lane << 3)];
            short8 b3 = *(const short8*)&sW1[((3 * 4 + nt) << 9) + (lane << 3)];
            acc[nt] = __builtin_amdgcn_mfma_f32_16x16x32_bf16(f0, b0, acc[nt], 0, 0, 0);
            acc[nt] = __builtin_amdgcn_mfma_f32_16x16x32_bf16(f1, b1, acc[nt], 0, 0, 0);
            acc[nt] = __builtin_amdgcn_mfma_f32_16x16x32_bf16(f2, b2, acc[nt], 0, 0, 0);
            acc[nt] = __builtin_amdgcn_mfma_f32_16x16x32_bf16(f3, b3, acc[nt], 0, 0, 0);
        }

        // ---- prefetch tile t+nw pos+frags, idx for t+2nw ----
        short8 g0, g1, g2, g3;
        float2 pd1, ps1;
        if (hasN) {
            pd1 = *(const float2*)(pos + (size_t)d1 * 2);
            ps1 = *(const float2*)(pos + (size_t)s1 * 2);
            g0 = *(const short8*)&hpb[(size_t)d1 * 64 + g * 8];
            g1 = *(const short8*)&hpb[(size_t)d1 * 64 + 32 + g * 8];
            g2 = *(const short8*)&hpb[(size_t)s1 * 64 + g * 8];
            g3 = *(const short8*)&hpb[(size_t)s1 * 64 + 32 + g * 8];
        }
        int s2 = 0, d2i = 0;
        if (hasNN) {
            int e = (t + 2 * nw) * 16 + c;
            s2 = ei[e]; d2i = ei[N_EDGES + e];
        }

        // d2 contribution + bias + silu -> t1 tile (bf16, XOR swizzle)
        float d2q[4];
        #pragma unroll
        for (int r = 0; r < 4; ++r) d2q[r] = __shfl(dist2, g * 4 + r, 64);
        #pragma unroll
        for (int nt = 0; nt < 4; ++nt) {
            #pragma unroll
            for (int r = 0; r < 4; ++r) {
                float v = silu_f(fmaf(d2q[r], w128f[nt], acc[nt][r] + bi1[nt]));
                int row = g * 4 + r;
                int idx = ((row << 6) + (nt << 4) + c) ^ ((row & 7) << 3);
                tile[idx] = f2bf(v);
            }
        }
        asm volatile("s_waitcnt lgkmcnt(0)" ::: "memory");
        __builtin_amdgcn_sched_barrier(0);

        // ---- layer 2: t1[16x64] @ W2[64x64] ----
        short8 a20, a21;
        {
            int row = c;
            int b0 = ((row << 6) + (g << 3)) ^ ((row & 7) << 3);
            int b1 = ((row << 6) + 32 + (g << 3)) ^ ((row & 7) << 3);
            a20 = *(const short8*)&tile[b0];
            a21 = *(const short8*)&tile[b1];
        }
        f32x4 acc2[4];
        #pragma unroll
        for (int nt = 0; nt < 4; ++nt) acc2[nt] = f32x4{0.f, 0.f, 0.f, 0.f};
        #pragma unroll
        for (int nt = 0; nt < 4; ++nt) {
            short8 b0 = *(const short8*)&sW2[(nt << 9) + (lane << 3)];
            short8 b1 = *(const short8*)&sW2[((4 + nt) << 9) + (lane << 3)];
            acc2[nt] = __builtin_amdgcn_mfma_f32_16x16x32_bf16(a20, b0, acc2[nt], 0, 0, 0);
            acc2[nt] = __builtin_amdgcn_mfma_f32_16x16x32_bf16(a21, b1, acc2[nt], 0, 0, 0);
        }
        float mv[4][4];
        #pragma unroll
        for (int nt = 0; nt < 4; ++nt) {
            #pragma unroll
            for (int r = 0; r < 4; ++r) mv[nt][r] = silu_f(acc2[nt][r] + bi2[nt]);
        }

        // write m tile for pos1 A-frags (t1 reads already consumed)
        asm volatile("s_waitcnt lgkmcnt(0)" ::: "memory");
        __builtin_amdgcn_sched_barrier(0);
        #pragma unroll
        for (int nt = 0; nt < 4; ++nt) {
            #pragma unroll
            for (int r = 0; r < 4; ++r) {
                int row = g * 4 + r;
                int idx = ((row << 6) + (nt << 4) + c) ^ ((row & 7) << 3);
                tile[idx] = f2bf(mv[nt][r]);
            }
        }
        // ---- agg scatter: packed bf16 atomics, 8 instr / 32 segments per tile ----
        #pragma unroll
        for (int r = 0; r < 4; ++r) {
            int q = g * 4 + r;
            int dstr = __shfl(d0, q, 64);
            unsigned lo = (unsigned)(unsigned short)f2bf(mv[0][r])
                        | ((unsigned)(unsigned short)f2bf(mv[1][r]) << 16);
            unsigned hi = (unsigned)(unsigned short)f2bf(mv[2][r])
                        | ((unsigned)(unsigned short)f2bf(mv[3][r]) << 16);
            char* base = (char*)aggb + (size_t)dstr * 128 + c * 4;
            atom_pk_bf16(base, lo);
            atom_pk_bf16(base + 64, hi);
        }
        asm volatile("s_waitcnt lgkmcnt(0)" ::: "memory");
        __builtin_amdgcn_sched_barrier(0);

        // ---- pos1: m[16x64] @ Wp1[64x64] ----
        short8 ap0, ap1;
        {
            int row = c;
            int b0 = ((row << 6) + (g << 3)) ^ ((row & 7) << 3);
            int b1 = ((row << 6) + 32 + (g << 3)) ^ ((row & 7) << 3);
            ap0 = *(const short8*)&tile[b0];
            ap1 = *(const short8*)&tile[b1];
        }
        f32x4 acc3[4];
        #pragma unroll
        for (int nt = 0; nt < 4; ++nt) acc3[nt] = f32x4{0.f, 0.f, 0.f, 0.f};
        #pragma unroll
        for (int nt = 0; nt < 4; ++nt) {
            short8 b0 = *(const short8*)&sWp[(nt << 9) + (lane << 3)];
            short8 b1 = *(const short8*)&sWp[((4 + nt) << 9) + (lane << 3)];
            acc3[nt] = __builtin_amdgcn_mfma_f32_16x16x32_bf16(ap0, b0, acc3[nt], 0, 0, 0);
            acc3[nt] = __builtin_amdgcn_mfma_f32_16x16x32_bf16(ap1, b1, acc3[nt], 0, 0, 0);
        }
        // ---- pos2 + fused posw/deg scatter: 1 atomic instr per r ----
        #pragma unroll
        for (int r = 0; r < 4; ++r) {
            float part = 0.f;
            #pragma unroll
            for (int nt = 0; nt < 4; ++nt)
                part = fmaf(silu_f(acc3[nt][r] + bip[nt]), wp2r[nt], part);
            part += __shfl_xor(part, 1, 64);
            part += __shfl_xor(part, 2, 64);
            part += __shfl_xor(part, 4, 64);
            part += __shfl_xor(part, 8, 64);
            float w = part + bp2v;
            int q = g * 4 + r;
            int dstr = __shfl(d0, q, 64);
            float rx = __shfl(relx, q, 64);
            float ry = __shfl(rely, q, 64);
            if (c < 3) {
                float val = (c == 0) ? rx * w : (c == 1) ? ry * w : 1.0f;
                atomicAdd(posw3 + (size_t)dstr * 4 + c, val);
            }
        }

        // ---- rotate pipeline registers ----
        s0 = s1; d0 = d1; pd0 = pd1; ps0 = ps1;
        f0 = g0; f1 = g1; f2 = g2; f3 = g3;
        s1 = s2; d1 = d2i;
    }
}

// ---------------- Kernel 2: node MLP via MFMA + outputs (f32) ----------------
// A = [bf16(h+h_init) | agg_bf16(interleaved sigma order)], K=128.
// sigma un-permutation folded into W_h1 B-frag staging.
__global__ __launch_bounds__(512)
void k_node(const float* __restrict__ h, const float* __restrict__ h_init,
            const short* __restrict__ hpb, const float* __restrict__ pos,
            const short* __restrict__ aggb, const float* __restrict__ posw3,
            const float* __restrict__ Wh1, const float* __restrict__ bh1,
            const float* __restrict__ Wh2, const float* __restrict__ bh2,
            float* __restrict__ out)
{
    __shared__ short sW1[8192];
    __shared__ short sW2[4096];
    __shared__ short sT[8][1024];

    for (int i = threadIdx.x; i < 8192; i += 512) {
        int j = i & 7, lane = (i >> 3) & 63, nt = (i >> 9) & 3, kk = i >> 11;
        int ks = kk * 32 + ((lane >> 4) << 3) + j;    // storage k
        int k;
        if (ks < 64) k = ks;
        else {
            int s = ks - 64;   // agg storage order -> semantic dim
            k = 64 + 16 * ((s & 1) + 2 * (s >> 5)) + ((s >> 1) & 15);
        }
        int n = (nt << 4) + (lane & 15);
        sW1[i] = f2bf(Wh1[k * 64 + n]);
    }
    for (int i = threadIdx.x; i < 4096; i += 512) {
        int j = i & 7, lane = (i >> 3) & 63, nt = (i >> 9) & 3, kk = i >> 11;
        int k = kk * 32 + ((lane >> 4) << 3) + j;
        int n = (nt << 4) + (lane & 15);
        sW2[i] = f2bf(Wh2[k * 64 + n]);
    }
    __syncthreads();

    const int lane = threadIdx.x & 63;
    const int wv   = threadIdx.x >> 6;
    const int g    = lane >> 4;
    const int c    = lane & 15;
    short* tile = &sT[wv][0];

    const int tl = blockIdx.x * 8 + wv;
    if (tl >= NODE_TILES) return;
    const int tb = tl * 16;

    float bi1[4], bi2[4];
    #pragma unroll
    for (int nt = 0; nt < 4; ++nt) {
        bi1[nt] = bh1[nt * 16 + c];
        bi2[nt] = bh2[nt * 16 + c];
    }

    const int node = tb + c;
    short8 a0 = *(const short8*)&hpb[(size_t)node * 64 + g * 8];
    short8 a1 = *(const short8*)&hpb[(size_t)node * 64 + 32 + g * 8];
    short8 a2 = *(const short8*)&aggb[(size_t)node * 64 + g * 8];
    short8 a3 = *(const short8*)&aggb[(size_t)node * 64 + 32 + g * 8];

    f32x4 acc[4];
    #pragma unroll
    for (int nt = 0; nt < 4; ++nt) acc[nt] = f32x4{0.f, 0.f, 0.f, 0.f};
    #pragma unroll
    for (int nt = 0; nt < 4; ++nt) {
        short8 b0 = *(const short8*)&sW1[((0 * 4 + nt) << 9) + (lane << 3)];
        short8 b1 = *(const short8*)&sW1[((1 * 4 + nt) << 9) + (lane << 3)];
        short8 b2 = *(const short8*)&sW1[((2 * 4 + nt) << 9) + (lane << 3)];
        short8 b3 = *(const short8*)&sW1[((3 * 4 + nt) << 9) + (lane << 3)];
        acc[nt] = __builtin_amdgcn_mfma_f32_16x16x32_bf16(a0, b0, acc[nt], 0, 0, 0);
        acc[nt] = __builtin_amdgcn_mfma_f32_16x16x32_bf16(a1, b1, acc[nt], 0, 0, 0);
        acc[nt] = __builtin_amdgcn_mfma_f32_16x16x32_bf16(a2, b2, acc[nt], 0, 0, 0);
        acc[nt] = __builtin_amdgcn_mfma_f32_16x16x32_bf16(a3, b3, acc[nt], 0, 0, 0);
    }
    #pragma unroll
    for (int nt = 0; nt < 4; ++nt) {
        #pragma unroll
        for (int r = 0; r < 4; ++r) {
            float v = silu_f(acc[nt][r] + bi1[nt]);
            int row = g * 4 + r;
            int idx = ((row << 6) + (nt << 4) + c) ^ ((row & 7) << 3);
            tile[idx] = f2bf(v);
        }
    }
    asm volatile("s_waitcnt lgkmcnt(0)" ::: "memory");
    __builtin_amdgcn_sched_barrier(0);

    short8 a20, a21;
    {
        int row = c;
        int b0 = ((row << 6) + (g << 3)) ^ ((row & 7) << 3);
        int b1 = ((row << 6) + 32 + (g << 3)) ^ ((row & 7) << 3);
        a20 = *(const short8*)&tile[b0];
        a21 = *(const short8*)&tile[b1];
    }
    f32x4 acc2[4];
    #pragma unroll
    for (int nt = 0; nt < 4; ++nt) acc2[nt] = f32x4{0.f, 0.f, 0.f, 0.f};
    #pragma unroll
    for (int nt = 0; nt < 4; ++nt) {
        short8 b0 = *(const short8*)&sW2[(nt << 9) + (lane << 3)];
        short8 b1 = *(const short8*)&sW2[((4 + nt) << 9) + (lane << 3)];
        acc2[nt] = __builtin_amdgcn_mfma_f32_16x16x32_bf16(a20, b0, acc2[nt], 0, 0, 0);
        acc2[nt] = __builtin_amdgcn_mfma_f32_16x16x32_bf16(a21, b1, acc2[nt], 0, 0, 0);
    }
    #pragma unroll
    for (int r = 0; r < 4; ++r) {
        int q = g * 4 + r;
        #pragma unroll
        for (int nt = 0; nt < 4; ++nt) {
            size_t idx = (size_t)(tb + q) * 64 + nt * 16 + c;
            out[idx] = h[idx] + h_init[idx] + acc2[nt][r] + bi2[nt];
        }
    }
    if (lane < 16) {
        int n2 = tb + lane;
        float dg = fmaxf(posw3[(size_t)n2 * 4 + 2], 1.0f);
        float inv = __builtin_amdgcn_rcpf(dg);
        float2 po = *(const float2*)(pos + (size_t)n2 * 2);
        float2 pw = *(const float2*)(posw3 + (size_t)n2 * 4);
        float2 res;
        res.x = po.x + pw.x * inv;
        res.y = po.y + pw.y * inv;
        *(float2*)(out + (size_t)N_NODES * DIM + (size_t)n2 * 2) = res;
    }
}

extern "C" void kernel_launch(void* const* d_in, const int* in_sizes, int n_in,
                              void* d_out, int out_size, void* d_ws, size_t ws_size,
                              hipStream_t stream) {
    const float* h      = (const float*)d_in[0];
    const float* pos    = (const float*)d_in[1];
    const float* h_init = (const float*)d_in[2];
    const float* Wm1    = (const float*)d_in[3];
    const float* bm1    = (const float*)d_in[4];
    const float* Wm2    = (const float*)d_in[5];
    const float* bm2    = (const float*)d_in[6];
    const float* Wp1    = (const float*)d_in[7];
    const float* bp1    = (const float*)d_in[8];
    const float* Wp2    = (const float*)d_in[9];
    const float* bp2    = (const float*)d_in[10];
    const float* Wh1    = (const float*)d_in[11];
    const float* bh1    = (const float*)d_in[12];
    const float* Wh2    = (const float*)d_in[13];
    const float* bh2    = (const float*)d_in[14];
    const void*  eidx   = (const void*)d_in[15];
    float* out = (float*)d_out;

    short* aggb   = (short*)d_ws;                          // N*64 bf16 (sigma order)
    float* posw3  = (float*)(aggb + (size_t)N_NODES * DIM); // N*4 {x,y,deg,pad}
    short* hpb    = (short*)(posw3 + (size_t)N_NODES * 4);  // N*64 bf16
    int*   eidx32 = (int*)(hpb + (size_t)N_NODES * DIM);    // 2E int32

    k_init<<<2048, 256, 0, stream>>>(h, h_init, hpb, (int*)aggb, posw3, eidx, eidx32);
    k_edge<<<768, 512, 0, stream>>>(hpb, pos, eidx32, Wm1, bm1, Wm2, bm2,
                                    Wp1, bp1, Wp2, bp2, aggb, posw3);
    k_node<<<(NODE_TILES + 7) / 8, 512, 0, stream>>>(h, h_init, hpb, pos, aggb, posw3,
                                                     Wh1, bh1, Wh2, bh2, out);
}